// Round 9
// baseline (14471.982 us; speedup 1.0000x reference)
//
#include <hip/hip_runtime.h>
#include <cstdint>
#include <cstddef>

#define S_LEN 512
#define NB    64
#define NI    1024
#define NH    1024
#define NR    4096   // 4 gates * NH, interleaved r = j*4 + g  (g: 0=i,1=f,2=c,3=o)
#define NGRP  4      // independent batch groups (16 batches each)
#define WPG   64     // WGs per group; each WG owns 64 weight rows = 16 j
#define BPG   16     // batches per group

typedef short bf16x8 __attribute__((ext_vector_type(8)));
typedef float f32x4  __attribute__((ext_vector_type(4)));

__device__ __forceinline__ short f2bf(float f) {
  uint32_t u = __float_as_uint(f);
  u += 0x7fff + ((u >> 16) & 1);          // RNE
  return (short)(u >> 16);
}
__device__ __forceinline__ float bf2f(short s) {
  return __uint_as_float(((uint32_t)(uint16_t)s) << 16);
}
__device__ __forceinline__ void gload16(const void* g, void* l) {
  __builtin_amdgcn_global_load_lds((const __attribute__((address_space(1))) void*)g,
                                   (__attribute__((address_space(3))) void*)l, 16, 0, 0);
}
__device__ __forceinline__ float sigm(float x) { return 1.0f / (1.0f + __expf(-x)); }
__device__ __forceinline__ float tanh_fast(float x) {
  return 2.0f / (1.0f + __expf(-2.0f * x)) - 1.0f;
}

// fabric-coherent ops (agent scope, relaxed) — single-copy-atomic 8B units
__device__ __forceinline__ void astore64(void* p, uint64_t v) {
  __hip_atomic_store((uint64_t*)p, v, __ATOMIC_RELAXED, __HIP_MEMORY_SCOPE_AGENT);
}
__device__ __forceinline__ uint64_t aload64(const void* p) {
  return __hip_atomic_load((const uint64_t*)p, __ATOMIC_RELAXED, __HIP_MEMORY_SCOPE_AGENT);
}

// LDS-only barrier (rule #18: fence the inline waitcnt with sched_barrier)
__device__ __forceinline__ void barrier_lds() {
  __builtin_amdgcn_sched_barrier(0);
  asm volatile("s_waitcnt lgkmcnt(0)" ::: "memory");
  __builtin_amdgcn_s_barrier();
  __builtin_amdgcn_sched_barrier(0);
}

// ---------------- prep kernels ----------------

__global__ __launch_bounds__(256) void k_convert_x(const float* __restrict__ x,
                                                   short* __restrict__ xbf) {
  int tid = blockIdx.x * 256 + threadIdx.x;        // exactly SB*NI/4 threads
  float4 v = ((const float4*)x)[tid];
  short4 o;
  o.x = f2bf(v.x); o.y = f2bf(v.y); o.z = f2bf(v.z); o.w = f2bf(v.w);
  ((short4*)xbf)[tid] = o;
}

struct WPtrs { const float *xi, *xf, *xc, *xo, *hi, *hf, *hc, *ho; };

__global__ __launch_bounds__(256) void k_pack_w(WPtrs w, short* __restrict__ wxcat,
                                                short* __restrict__ whcat) {
  int tid  = blockIdx.x * 256 + threadIdx.x;       // NR*NI/4 threads
  int flat = tid * 4;
  int r = flat >> 10, k = flat & 1023;
  int j = r >> 2, g = r & 3;
  const float* px = (g == 0) ? w.xi : (g == 1) ? w.xf : (g == 2) ? w.xc : w.xo;
  const float* ph = (g == 0) ? w.hi : (g == 1) ? w.hf : (g == 2) ? w.hc : w.ho;
  float4 vx = *(const float4*)(px + j * 1024 + k);
  float4 vh = *(const float4*)(ph + j * 1024 + k);
  short4 ox, oh;
  ox.x = f2bf(vx.x); ox.y = f2bf(vx.y); ox.z = f2bf(vx.z); ox.w = f2bf(vx.w);
  oh.x = f2bf(vh.x); oh.y = f2bf(vh.y); oh.z = f2bf(vh.z); oh.w = f2bf(vh.w);
  *(short4*)(wxcat + flat) = ox;
  *(short4*)(whcat + flat) = oh;
}

struct BPtrs { const float *xi,*hi,*i_, *xf,*hf,*f_, *xc,*hc,*c_, *xo,*ho,*o_; };

__global__ __launch_bounds__(256) void k_init(BPtrs p, float* __restrict__ bias) {
  int tid = blockIdx.x * 256 + threadIdx.x;        // NR = 4096 threads
  int j = tid >> 2, g = tid & 3;
  const float* bx = (g == 0) ? p.xi : (g == 1) ? p.xf : (g == 2) ? p.xc : p.xo;
  const float* bh = (g == 0) ? p.hi : (g == 1) ? p.hf : (g == 2) ? p.hc : p.ho;
  const float* bb = (g == 0) ? p.i_ : (g == 1) ? p.f_ : (g == 2) ? p.c_ : p.o_;
  bias[tid] = bx[j] + bh[j] + bb[j];
}

// ---------------- phase 1: gx = x @ Wx^T + bias  (bf16 MFMA, 128x128 tile) --------------

__global__ __launch_bounds__(256) void gemm_x(const short* __restrict__ xbf,  // [32768][1024]
                                              const short* __restrict__ wx,   // [4096][1024]
                                              const float* __restrict__ bias, // [4096]
                                              short* __restrict__ gx) {       // [32768][4096]
  __shared__ __align__(16) short As[2][4096];   // [128][32] bf16, 64B rows
  __shared__ __align__(16) short Bs[2][4096];

  const int tid = threadIdx.x, wave = tid >> 6, lane = tid & 63;
  const int m0 = blockIdx.x * 128, n0 = blockIdx.y * 128;
  const char* aB = (const char*)xbf + (size_t)m0 * 2048;
  const char* bB = (const char*)wx + (size_t)n0 * 2048;

  f32x4 acc[4][4] = {};

  auto stage = [&](int kt, int buf) {
#pragma unroll
    for (int s2 = 0; s2 < 2; ++s2) {
      int seg = wave * 2 + s2;
      int L   = seg * 1024 + lane * 16;
      int row = L >> 6;           // 64-B rows
      int cb  = L & 63;
      gload16(aB + (size_t)row * 2048 + kt * 64 + cb, (char*)&As[buf][0] + L);
      gload16(bB + (size_t)row * 2048 + kt * 64 + cb, (char*)&Bs[buf][0] + L);
    }
  };

  const int wm = wave >> 1, wn = wave & 1;
  auto compute = [&](int buf) {
    const char* Ab = (const char*)&As[buf][0];
    const char* Bb = (const char*)&Bs[buf][0];
    bf16x8 a[4], b[4];
#pragma unroll
    for (int f = 0; f < 4; ++f) {
      int ar = wm * 64 + f * 16 + (lane & 15);
      a[f] = *(const bf16x8*)(Ab + ar * 64 + (lane >> 4) * 16);
      int br = wn * 64 + f * 16 + (lane & 15);
      b[f] = *(const bf16x8*)(Bb + br * 64 + (lane >> 4) * 16);
    }
#pragma unroll
    for (int i = 0; i < 4; ++i)
#pragma unroll
      for (int j = 0; j < 4; ++j)
        acc[i][j] = __builtin_amdgcn_mfma_f32_16x16x32_bf16(a[i], b[j], acc[i][j], 0, 0, 0);
  };

  stage(0, 0);
  __syncthreads();
  int buf = 0;
  for (int kt = 0; kt < 32; ++kt) {
    if (kt < 31) stage(kt + 1, buf ^ 1);
    compute(buf);
    __syncthreads();
    buf ^= 1;
  }

  const int colL = lane & 15;
#pragma unroll
  for (int j = 0; j < 4; ++j) {
    int   n  = n0 + wn * 64 + j * 16 + colL;
    float bv = bias[n];
#pragma unroll
    for (int i = 0; i < 4; ++i) {
#pragma unroll
      for (int q = 0; q < 4; ++q) {
        int m = m0 + wm * 64 + i * 16 + (lane >> 4) * 4 + q;
        __builtin_nontemporal_store((short)f2bf(acc[i][j][q] + bv),
                                    &gx[(size_t)m * NR + n]);   // streaming 268 MB write
      }
    }
  }
}

// ---------------- persistent recurrence kernel: tagged-data exchange ----------------
// 256 WGs x 256 threads, 1/CU. Group g = blockIdx&3 owns batches [g*16,g*16+16);
// WG wq = blockIdx>>2 owns weight rows [wq*64,+64) == j in [wq*16,+16).
// h exchange: per (b, j-pair) one atomic u64 {hi=tag=t+1, lo=2xbf16}. Consumers
// poll the data words directly (uncached) — no drain, no flags, no barrier.
// 2-slot ping-pong per group; safety proof in round-9 notes (publish of h_t is
// data-dependent on reads of h_{t-1}, so full tag-set t implies all h_{t-1}
// reads retired; consumer can never observe tag t+2 while wanting t).
//
// LDS: [0,131072) Wh 64rows x 1024k bf16 (2048-B rows, XOR-swz); pre[2][16][65] f32.
#define LDS_BYTES (131072 + 2 * 16 * 65 * 4)
// hbuf: [grp][slot=2][b=16][jpair=512] u64
#define HB_SLOT_U64 (16 * 512)
#define HB_GRP_U64  (2 * HB_SLOT_U64)

__global__ __launch_bounds__(256, 1) void lstm_persist(
    const short* __restrict__ gx,   // [S][64][4096]
    const short* __restrict__ wh,   // [4096][1024]
    uint64_t* __restrict__ hbuf,    // tagged h exchange
    float* __restrict__ out) {
  extern __shared__ __align__(16) char lds[];
  char* WhC = lds;
  float (*pre)[16][65] = (float(*)[16][65])(lds + 131072);

  const int tid = threadIdx.x, wave = tid >> 6, lane = tid & 63;
  const int grp = blockIdx.x & 3;
  const int wq  = blockIdx.x >> 2;
  const int r0  = wq * 64;          // first weight row
  const int j0  = wq * 16;          // first hidden unit
  const char* whB = (const char*)(wh + (size_t)r0 * NH);
  uint64_t* hb_g = hbuf + (size_t)grp * HB_GRP_U64;

  // ---- load Wh once (64 rows x 2 KB), swizzled via pre-swizzled source ----
#pragma unroll
  for (int p = 0; p < 32; ++p) {
    int L = p * 4096 + tid * 16;
    int row = L >> 11, kb = L & 2047;
    gload16(whB + (size_t)row * 2048 + (kb ^ ((row & 7) << 4)), lds + L);
  }

  // pointwise ownership (tid < 128): b in [0,16), jp in [0,8)
  const int b_pw = tid >> 3;
  const int jp   = tid & 7;
  float c_reg[2] = {0.f, 0.f};

  // A-fragment: batch row + k-chunk (j-pair block) per lane — all waves identical
  const int am    = lane & 15;
  const int jpofs = (lane >> 4) * 4;     // 4 consecutive j-pairs per lane chunk
  // B (Wh) fragment: wave owns rows [wave*16, wave*16+16)
  const int br   = wave * 16 + (lane & 15);
  const int bswz = (br & 7) << 4;
  const int bcol = (lane >> 4) * 16;

  // this thread's gx address (r = j*4+g interleaved; 8 gates for j pair = 16 B)
  const short* gx_me = gx + ((size_t)grp * BPG + b_pw) * NR + j0 * 4 + jp * 8;

  __syncthreads();   // Wh resident (compiler drains vmcnt for global_load_lds)

  bf16x8 gx_cur = {}, gx_nxt = {};
  if (tid < 128) gx_cur = *(const bf16x8*)(gx_me);   // t = 0

  for (int t = 0; t < S_LEN; ++t) {
    f32x4 acc0 = {}, acc1 = {};

    if (t) {   // consume h_{t-1}: tagged-data poll, tag must equal t
      const uint64_t want = (uint64_t)t;
      const uint64_t* hrow = hb_g + (size_t)((t - 1) & 1) * HB_SLOT_U64 + (size_t)am * 512;
      bf16x8 a[32];
      for (;;) {
        bool ok = true;
#pragma unroll
        for (int ks = 0; ks < 32; ++ks) {
          const uint64_t* p = hrow + ks * 16 + jpofs;
          uint64_t w0 = aload64(p + 0);
          uint64_t w1 = aload64(p + 1);
          uint64_t w2 = aload64(p + 2);
          uint64_t w3 = aload64(p + 3);
          ok &= ((w0 >> 32) == want) & ((w1 >> 32) == want) &
                ((w2 >> 32) == want) & ((w3 >> 32) == want);
          union { uint32_t d[4]; bf16x8 v; } u;
          u.d[0] = (uint32_t)w0; u.d[1] = (uint32_t)w1;
          u.d[2] = (uint32_t)w2; u.d[3] = (uint32_t)w3;
          a[ks] = u.v;
        }
        if (__all(ok)) break;
        __builtin_amdgcn_s_sleep(1);
      }

      // gx prefetch for t+1 in the MFMA shadow (cached; used only next step)
      if (tid < 128) {
        const int tp = (t + 1 < S_LEN) ? t + 1 : t;
        gx_nxt = *(const bf16x8*)(gx_me + (size_t)tp * NB * NR);
      }

#pragma unroll
      for (int ks = 0; ks < 32; ++ks) {
        int wb = ks * 64 + bcol;
        bf16x8 b0 = *(const bf16x8*)(WhC + br * 2048 + (wb ^ bswz));
        if (ks & 1) acc1 = __builtin_amdgcn_mfma_f32_16x16x32_bf16(a[ks], b0, acc1, 0, 0, 0);
        else        acc0 = __builtin_amdgcn_mfma_f32_16x16x32_bf16(a[ks], b0, acc0, 0, 0, 0);
      }
    } else if (tid < 128) {
      gx_nxt = *(const bf16x8*)(gx_me + (size_t)NB * NR);   // t=0: prefetch t=1
    }

    // park pre-activations in LDS (parity buffer; MFMA C layout -> [b][r_local])
    const int par = t & 1;
    {
      f32x4 a0 = acc0 + acc1;
      const int colL = lane & 15;            // r within wave's 16-row block
      const int mB   = (lane >> 4) * 4;      // batch base
#pragma unroll
      for (int q = 0; q < 4; ++q)
        pre[par][mB + q][wave * 16 + colL] = a0[q];
    }
    barrier_lds();   // intra-WG LDS ordering only (protocol needs no vmcnt drain)

    // pointwise + tagged publish: threads 0..127, one (b, j-pair) each
    if (tid < 128) {
      float hn2[2];
#pragma unroll
      for (int it = 0; it < 2; ++it) {
        int rl = (jp * 2 + it) * 4;          // local row of gate i
        float vi = pre[par][b_pw][rl + 0] + bf2f(gx_cur[it * 4 + 0]);
        float vf = pre[par][b_pw][rl + 1] + bf2f(gx_cur[it * 4 + 1]);
        float vg = pre[par][b_pw][rl + 2] + bf2f(gx_cur[it * 4 + 2]);
        float vo = pre[par][b_pw][rl + 3] + bf2f(gx_cur[it * 4 + 3]);
        float ig = sigm(vi), fg = sigm(vf), gg = tanh_fast(vg), og = sigm(vo);
        c_reg[it] = fg * c_reg[it] + ig * gg;
        hn2[it]   = og * tanh_fast(c_reg[it]);
      }
      uint32_t hbits = (uint32_t)(uint16_t)f2bf(hn2[0]) |
                       ((uint32_t)(uint16_t)f2bf(hn2[1]) << 16);
      if (t != S_LEN - 1) {
        uint64_t* hw = hb_g + (size_t)(t & 1) * HB_SLOT_U64 + (size_t)b_pw * 512
                     + (wq * 8 + jp);
        astore64(hw, ((uint64_t)(t + 1) << 32) | hbits);   // data+tag, one atomic
      }
      float2 of = { hn2[0], hn2[1] };
      *(float2*)(out + ((size_t)t * NB + grp * BPG + b_pw) * NH + j0 + jp * 2) = of;
      if (t == S_LEN - 1) {
        float* oh = out + (size_t)S_LEN * NB * NH;
        int ci = (grp * BPG + b_pw) * NH + j0 + jp * 2;
        *(float2*)(oh + ci) = of;                                  // final h
        float2 cf = { c_reg[0], c_reg[1] };
        *(float2*)(oh + NB * NH + ci) = cf;                        // final c
      }
      gx_cur = gx_nxt;
    }
  }
}

// ---------------- launch ----------------

extern "C" void kernel_launch(void* const* d_in, const int* in_sizes, int n_in,
                              void* d_out, int out_size, void* d_ws, size_t ws_size,
                              hipStream_t stream) {
  const float* x   = (const float*)d_in[0];
  const float* wxi = (const float*)d_in[1];
  const float* bxi = (const float*)d_in[2];
  const float* whi = (const float*)d_in[3];
  const float* bhi = (const float*)d_in[4];
  const float* bi  = (const float*)d_in[5];
  const float* wxf = (const float*)d_in[6];
  const float* bxf = (const float*)d_in[7];
  const float* whf = (const float*)d_in[8];
  const float* bhf = (const float*)d_in[9];
  const float* bf  = (const float*)d_in[10];
  const float* wxc = (const float*)d_in[11];
  const float* bxc = (const float*)d_in[12];
  const float* whc = (const float*)d_in[13];
  const float* bhc = (const float*)d_in[14];
  const float* bc  = (const float*)d_in[15];
  const float* wxo = (const float*)d_in[16];
  const float* bxo = (const float*)d_in[17];
  const float* who = (const float*)d_in[18];
  const float* bho = (const float*)d_in[19];
  const float* bo  = (const float*)d_in[20];

  char* ws = (char*)d_ws;
  const size_t SB = (size_t)S_LEN * NB;
  size_t off = 0;
  short* gxp   = (short*)(ws + off); off += SB * NR * 2;        // 268 MB
  short* xbf   = (short*)(ws + off); off += SB * NI * 2;        // 67 MB
  short* wxcat = (short*)(ws + off); off += (size_t)NR * NI * 2;
  short* whcat = (short*)(ws + off); off += (size_t)NR * NH * 2;
  float* bias  = (float*)(ws + off); off += NR * 4;
  uint64_t* hbuf = (uint64_t*)(ws + off); off += (size_t)NGRP * HB_GRP_U64 * 8; // 512 KB
  (void)ws_size; (void)in_sizes; (void)n_in; (void)out_size;

  float* out = (float*)d_out;

  (void)hipFuncSetAttribute((const void*)lstm_persist,
                            hipFuncAttributeMaxDynamicSharedMemorySize, LDS_BYTES);

  // zero ALL tags every call (replay-safe: stale tags from a previous call
  // share parity with fresh wants and would be accepted otherwise)
  hipMemsetAsync(hbuf, 0, (size_t)NGRP * HB_GRP_U64 * 8, stream);

  k_convert_x<<<(int)(SB * NI / 4 / 256), 256, 0, stream>>>(x, xbf);
  WPtrs wp = {wxi, wxf, wxc, wxo, whi, whf, whc, who};
  k_pack_w<<<(NR * NI / 4) / 256, 256, 0, stream>>>(wp, wxcat, whcat);
  BPtrs bp = {bxi, bhi, bi, bxf, bhf, bf, bxc, bhc, bc, bxo, bho, bo};
  k_init<<<NR / 256, 256, 0, stream>>>(bp, bias);

  gemm_x<<<dim3(SB / 128, NR / 128), 256, 0, stream>>>(xbf, wxcat, bias, gxp);

  lstm_persist<<<NGRP * WPG, 256, LDS_BYTES, stream>>>(gxp, whcat, hbuf, out);
}

// Round 10
// 2194.072 us; speedup vs baseline: 6.5959x; 6.5959x over previous
//
#include <hip/hip_runtime.h>
#include <cstdint>
#include <cstddef>

#define S_LEN 512
#define NB    64
#define NI    1024
#define NH    1024
#define NR    4096   // 4 gates * NH, interleaved r = j*4 + g  (g: 0=i,1=f,2=c,3=o)
#define NGRP  4      // independent batch groups (16 batches each)
#define WPG   64     // WGs per group; each WG owns 64 weight rows = 16 j
#define BPG   16     // batches per group
#define HSLOT 33792  // per-step h slot: [wq=64][b=16][jl=16] bf16 (32 KB) + 1 KB pad
#define FLAGSTRIDE 16   // dwords between barrier flags (64 B)

typedef short bf16x8 __attribute__((ext_vector_type(8)));
typedef float f32x4  __attribute__((ext_vector_type(4)));

__device__ __forceinline__ short f2bf(float f) {
  uint32_t u = __float_as_uint(f);
  u += 0x7fff + ((u >> 16) & 1);          // RNE
  return (short)(u >> 16);
}
__device__ __forceinline__ float bf2f(short s) {
  return __uint_as_float(((uint32_t)(uint16_t)s) << 16);
}
__device__ __forceinline__ void gload16(const void* g, void* l) {
  __builtin_amdgcn_global_load_lds((const __attribute__((address_space(1))) void*)g,
                                   (__attribute__((address_space(3))) void*)l, 16, 0, 0);
}
__device__ __forceinline__ float sigm(float x) { return 1.0f / (1.0f + __expf(-x)); }
__device__ __forceinline__ float tanh_fast(float x) {
  return 2.0f / (1.0f + __expf(-2.0f * x)) - 1.0f;
}

// fabric write-through / uncached read (no fences needed; r3-r8 proven)
__device__ __forceinline__ void astore32(void* p, uint32_t v) {
  __hip_atomic_store((uint32_t*)p, v, __ATOMIC_RELAXED, __HIP_MEMORY_SCOPE_AGENT);
}
__device__ __forceinline__ uint32_t aload32(const void* p) {
  return __hip_atomic_load((const uint32_t*)p, __ATOMIC_RELAXED, __HIP_MEMORY_SCOPE_AGENT);
}

// ---------------- prep kernels ----------------

__global__ __launch_bounds__(256) void k_convert_x(const float* __restrict__ x,
                                                   short* __restrict__ xbf) {
  int tid = blockIdx.x * 256 + threadIdx.x;        // exactly SB*NI/4 threads
  float4 v = ((const float4*)x)[tid];
  short4 o;
  o.x = f2bf(v.x); o.y = f2bf(v.y); o.z = f2bf(v.z); o.w = f2bf(v.w);
  ((short4*)xbf)[tid] = o;
}

struct WPtrs { const float *xi, *xf, *xc, *xo, *hi, *hf, *hc, *ho; };

__global__ __launch_bounds__(256) void k_pack_w(WPtrs w, short* __restrict__ wxcat,
                                                short* __restrict__ whcat) {
  int tid  = blockIdx.x * 256 + threadIdx.x;       // NR*NI/4 threads
  int flat = tid * 4;
  int r = flat >> 10, k = flat & 1023;
  int j = r >> 2, g = r & 3;
  const float* px = (g == 0) ? w.xi : (g == 1) ? w.xf : (g == 2) ? w.xc : w.xo;
  const float* ph = (g == 0) ? w.hi : (g == 1) ? w.hf : (g == 2) ? w.hc : w.ho;
  float4 vx = *(const float4*)(px + j * 1024 + k);
  float4 vh = *(const float4*)(ph + j * 1024 + k);
  short4 ox, oh;
  ox.x = f2bf(vx.x); ox.y = f2bf(vx.y); ox.z = f2bf(vx.z); ox.w = f2bf(vx.w);
  oh.x = f2bf(vh.x); oh.y = f2bf(vh.y); oh.z = f2bf(vh.z); oh.w = f2bf(vh.w);
  *(short4*)(wxcat + flat) = ox;
  *(short4*)(whcat + flat) = oh;
}

struct BPtrs { const float *xi,*hi,*i_, *xf,*hf,*f_, *xc,*hc,*c_, *xo,*ho,*o_; };

__global__ __launch_bounds__(256) void k_init(BPtrs p, float* __restrict__ bias,
                                              unsigned int* __restrict__ flags) {
  int tid = blockIdx.x * 256 + threadIdx.x;        // NR = 4096 threads
  flags[tid] = 0;                                  // 4 grp x 64 wg x 16 = 4096 flags
  int j = tid >> 2, g = tid & 3;
  const float* bx = (g == 0) ? p.xi : (g == 1) ? p.xf : (g == 2) ? p.xc : p.xo;
  const float* bh = (g == 0) ? p.hi : (g == 1) ? p.hf : (g == 2) ? p.hc : p.ho;
  const float* bb = (g == 0) ? p.i_ : (g == 1) ? p.f_ : (g == 2) ? p.c_ : p.o_;
  bias[tid] = bx[j] + bh[j] + bb[j];
}

// ---------------- phase 1: gx = x @ Wx^T + bias  (bf16 MFMA, 128x128 tile) --------------

__global__ __launch_bounds__(256) void gemm_x(const short* __restrict__ xbf,  // [32768][1024]
                                              const short* __restrict__ wx,   // [4096][1024]
                                              const float* __restrict__ bias, // [4096]
                                              short* __restrict__ gx) {       // [32768][4096]
  __shared__ __align__(16) short As[2][4096];   // [128][32] bf16, 64B rows
  __shared__ __align__(16) short Bs[2][4096];

  const int tid = threadIdx.x, wave = tid >> 6, lane = tid & 63;
  const int m0 = blockIdx.x * 128, n0 = blockIdx.y * 128;
  const char* aB = (const char*)xbf + (size_t)m0 * 2048;
  const char* bB = (const char*)wx + (size_t)n0 * 2048;

  f32x4 acc[4][4] = {};

  auto stage = [&](int kt, int buf) {
#pragma unroll
    for (int s2 = 0; s2 < 2; ++s2) {
      int seg = wave * 2 + s2;
      int L   = seg * 1024 + lane * 16;
      int row = L >> 6;           // 64-B rows
      int cb  = L & 63;
      gload16(aB + (size_t)row * 2048 + kt * 64 + cb, (char*)&As[buf][0] + L);
      gload16(bB + (size_t)row * 2048 + kt * 64 + cb, (char*)&Bs[buf][0] + L);
    }
  };

  const int wm = wave >> 1, wn = wave & 1;
  auto compute = [&](int buf) {
    const char* Ab = (const char*)&As[buf][0];
    const char* Bb = (const char*)&Bs[buf][0];
    bf16x8 a[4], b[4];
#pragma unroll
    for (int f = 0; f < 4; ++f) {
      int ar = wm * 64 + f * 16 + (lane & 15);
      a[f] = *(const bf16x8*)(Ab + ar * 64 + (lane >> 4) * 16);
      int br = wn * 64 + f * 16 + (lane & 15);
      b[f] = *(const bf16x8*)(Bb + br * 64 + (lane >> 4) * 16);
    }
#pragma unroll
    for (int i = 0; i < 4; ++i)
#pragma unroll
      for (int j = 0; j < 4; ++j)
        acc[i][j] = __builtin_amdgcn_mfma_f32_16x16x32_bf16(a[i], b[j], acc[i][j], 0, 0, 0);
  };

  stage(0, 0);
  __syncthreads();
  int buf = 0;
  for (int kt = 0; kt < 32; ++kt) {
    if (kt < 31) stage(kt + 1, buf ^ 1);
    compute(buf);
    __syncthreads();
    buf ^= 1;
  }

  const int colL = lane & 15;
#pragma unroll
  for (int j = 0; j < 4; ++j) {
    int   n  = n0 + wn * 64 + j * 16 + colL;
    float bv = bias[n];
#pragma unroll
    for (int i = 0; i < 4; ++i) {
#pragma unroll
      for (int q = 0; q < 4; ++q) {
        int m = m0 + wm * 64 + i * 16 + (lane >> 4) * 4 + q;
        __builtin_nontemporal_store((short)f2bf(acc[i][j][q] + bv),
                                    &gx[(size_t)m * NR + n]);   // streaming 268 MB write
      }
    }
  }
}

// ---------------- persistent recurrence kernel: 4 independent groups ----------------
// 256 WGs x 256 threads, 1 WG/CU (launch_bounds(256,1) -> full VGPR budget so
// the 32 h-fragment loads stay a PARALLEL miss wave, not a serial chain —
// r8's VGPR=44 showed the compiler serializing them = the hidden ~3 us/step).
// Group g = blockIdx&3 owns batches [g*16,+16); WG wq = blockIdx>>2 owns weight
// rows [wq*64,+64) == j in [wq*16,+16). Wh in LDS XOR-swz; c in regs.
// h slots rotate (fresh address/step, never reused) with layout [wq][b][jl]:
// producer WG writes one contiguous 512-B block = 8 exclusively-owned lines
// (no cross-WG write-combining ping-pong). Flag protocol identical to r5/r8.
//
// LDS: [0,131072) Wh 64rows x 1024k bf16 (2048-B rows, XOR-swz); pre[2][16][65] f32.
#define LDS_BYTES (131072 + 2 * 16 * 65 * 4)

__global__ __launch_bounds__(256, 1) void lstm_persist(
    const short* __restrict__ gx,   // [S][64][4096]
    const short* __restrict__ wh,   // [4096][1024]
    char* __restrict__ hb,          // rotating h slots: [grp][S][HSLOT]
    unsigned int* __restrict__ flags, // [NGRP][WPG*FLAGSTRIDE]
    float* __restrict__ out) {
  extern __shared__ __align__(16) char lds[];
  char* WhC = lds;
  float (*pre)[16][65] = (float(*)[16][65])(lds + 131072);

  const int tid = threadIdx.x, wave = tid >> 6, lane = tid & 63;
  const int grp = blockIdx.x & 3;
  const int wq  = blockIdx.x >> 2;
  const int r0  = wq * 64;          // first weight row
  const int j0  = wq * 16;          // first hidden unit
  const char* whB = (const char*)(wh + (size_t)r0 * NH);
  char* hb_g = hb + (size_t)grp * S_LEN * HSLOT;
  unsigned int* flags_g = flags + grp * WPG * FLAGSTRIDE;

  // ---- load Wh once (64 rows x 2 KB), swizzled via pre-swizzled source ----
#pragma unroll
  for (int p = 0; p < 32; ++p) {
    int L = p * 4096 + tid * 16;
    int row = L >> 11, kb = L & 2047;
    gload16(whB + (size_t)row * 2048 + (kb ^ ((row & 7) << 4)), lds + L);
  }

  // pointwise ownership (tid < 128): b in [0,16), jp in [0,8)
  const int b_pw = tid >> 3;
  const int jp   = tid & 7;
  float c_reg[2] = {0.f, 0.f};

  // A-fragment per-lane constant offset into the [wq][b][jl] slot layout:
  // MFMA k-chunk ks covers global j = ks*32 + (lane>>4)*8 .. +8, batch = lane&15.
  // addr = slot + wq_k*512 + b*32 + jl0*2  with wq_k = ks*2 + (lane>>5),
  // jl0 = ((lane>>4)&1)*8  ->  slot + aoff + ks*1024.
  const int aoff = (lane >> 5) * 512 + (lane & 15) * 32 + ((lane >> 4) & 1) * 16;
  // B (Wh) fragment: wave owns rows [wave*16, wave*16+16)
  const int br   = wave * 16 + (lane & 15);
  const int bswz = (br & 7) << 4;
  const int bcol = (lane >> 4) * 16;

  // barrier poll: wave 0, lane l watches group flag l
  const unsigned int* fpoll = flags_g + lane * FLAGSTRIDE;

  // this thread's gx address (r = j*4+g interleaved; 8 gates for j pair = 16 B)
  const short* gx_me = gx + ((size_t)grp * BPG + b_pw) * NR + j0 * 4 + jp * 8;

  __syncthreads();   // Wh resident (vmcnt drained by compiler before barrier)

  bf16x8 gx_cur = {}, gx_nxt = {};
  if (tid < 128) gx_cur = *(const bf16x8*)(gx_me);   // t = 0

  for (int t = 0; t < S_LEN; ++t) {
    f32x4 acc0 = {}, acc1 = {};
    if (t) {   // t=0: h=0 -> matvec contributes nothing
      const char* hs = hb_g + (size_t)(t - 1) * HSLOT + aoff;
      // ---- all 32 cached 16-B loads issued as ONE wave (512-VGPR budget) ----
      bf16x8 a[32];
#pragma unroll
      for (int ks = 0; ks < 32; ++ks)
        a[ks] = *(const bf16x8*)(hs + ks * 1024);
      __builtin_amdgcn_sched_barrier(0);   // pin: loads issue before MFMA region
#pragma unroll
      for (int ks = 0; ks < 32; ++ks) {
        int wb = ks * 64 + bcol;
        bf16x8 b0 = *(const bf16x8*)(WhC + br * 2048 + (wb ^ bswz));
        if (ks & 1) acc1 = __builtin_amdgcn_mfma_f32_16x16x32_bf16(a[ks], b0, acc1, 0, 0, 0);
        else        acc0 = __builtin_amdgcn_mfma_f32_16x16x32_bf16(a[ks], b0, acc0, 0, 0, 0);
      }
    }

    // park pre-activations in LDS (parity buffer; MFMA C layout -> [b][r_local])
    const int par = t & 1;
    {
      f32x4 a0 = acc0 + acc1;
      const int colL = lane & 15;            // r within wave's 16-row block
      const int mB   = (lane >> 4) * 4;      // batch base
#pragma unroll
      for (int q = 0; q < 4; ++q)
        pre[par][mB + q][wave * 16 + colL] = a0[q];
    }
    __syncthreads();

    // pointwise: threads 0..127, one (b, j-pair) each; publish h write-through
    float hn2[2] = {0.f, 0.f};
    if (tid < 128) {
#pragma unroll
      for (int it = 0; it < 2; ++it) {
        int rl = (jp * 2 + it) * 4;          // local row of gate i
        float vi = pre[par][b_pw][rl + 0] + bf2f(gx_cur[it * 4 + 0]);
        float vf = pre[par][b_pw][rl + 1] + bf2f(gx_cur[it * 4 + 1]);
        float vg = pre[par][b_pw][rl + 2] + bf2f(gx_cur[it * 4 + 2]);
        float vo = pre[par][b_pw][rl + 3] + bf2f(gx_cur[it * 4 + 3]);
        float ig = sigm(vi), fg = sigm(vf), gg = tanh_fast(vg), og = sigm(vo);
        c_reg[it] = fg * c_reg[it] + ig * gg;
        hn2[it]   = og * tanh_fast(c_reg[it]);
      }
      if (t != S_LEN - 1) {
        // [wq][b][jl] slot layout: WG-contiguous 512-B block, exclusive lines
        char* hw = hb_g + (size_t)t * HSLOT + wq * 512 + b_pw * 32 + jp * 4;
        uint32_t hbits = (uint32_t)(uint16_t)f2bf(hn2[0]) |
                         ((uint32_t)(uint16_t)f2bf(hn2[1]) << 16);
        astore32(hw, hbits);
      }
    }

    if (t != S_LEN - 1) {
      __syncthreads();   // FULL drain: h stores acked at coherence point
      const unsigned want = (unsigned)(t + 1);
      if (tid == 0) astore32((void*)(flags_g + wq * FLAGSTRIDE), want);
    }

    // out stores AFTER the flag (cached; outside the h protocol — drained by
    // the next step's sync or kernel end)
    if (tid < 128) {
      float2 of = { hn2[0], hn2[1] };
      *(float2*)(out + ((size_t)t * NB + grp * BPG + b_pw) * NH + j0 + jp * 2) = of;
      if (t == S_LEN - 1) {
        float* oh = out + (size_t)S_LEN * NB * NH;
        int ci = (grp * BPG + b_pw) * NH + j0 + jp * 2;
        *(float2*)(oh + ci) = of;                                  // final h
        float2 cf = { c_reg[0], c_reg[1] };
        *(float2*)(oh + NB * NH + ci) = cf;                        // final c
      }
    }

    if (t != S_LEN - 1) {
      // gx prefetch for t+1 in the poll shadow
      if (tid < 128) {
        const int tp = (t + 1 < S_LEN) ? t + 1 : t;
        gx_nxt = *(const bf16x8*)(gx_me + (size_t)tp * NB * NR);
      }
      const unsigned want = (unsigned)(t + 1);
      if (wave == 0) {
        uint32_t v = aload32(fpoll);
        while (!__all(v >= want)) {
          __builtin_amdgcn_s_sleep(1);
          v = aload32(fpoll);
        }
      }
      __syncthreads();   // release: h slot t visible & fresh for everyone
      gx_cur = gx_nxt;
    }
  }
}

// ---------------- launch ----------------

extern "C" void kernel_launch(void* const* d_in, const int* in_sizes, int n_in,
                              void* d_out, int out_size, void* d_ws, size_t ws_size,
                              hipStream_t stream) {
  const float* x   = (const float*)d_in[0];
  const float* wxi = (const float*)d_in[1];
  const float* bxi = (const float*)d_in[2];
  const float* whi = (const float*)d_in[3];
  const float* bhi = (const float*)d_in[4];
  const float* bi  = (const float*)d_in[5];
  const float* wxf = (const float*)d_in[6];
  const float* bxf = (const float*)d_in[7];
  const float* whf = (const float*)d_in[8];
  const float* bhf = (const float*)d_in[9];
  const float* bf  = (const float*)d_in[10];
  const float* wxc = (const float*)d_in[11];
  const float* bxc = (const float*)d_in[12];
  const float* whc = (const float*)d_in[13];
  const float* bhc = (const float*)d_in[14];
  const float* bc  = (const float*)d_in[15];
  const float* wxo = (const float*)d_in[16];
  const float* bxo = (const float*)d_in[17];
  const float* who = (const float*)d_in[18];
  const float* bho = (const float*)d_in[19];
  const float* bo  = (const float*)d_in[20];

  char* ws = (char*)d_ws;
  const size_t SB = (size_t)S_LEN * NB;
  size_t off = 0;
  short* gxp   = (short*)(ws + off); off += SB * NR * 2;        // 268 MB
  short* xbf   = (short*)(ws + off); off += SB * NI * 2;        // 67 MB (dead after gemm_x)
  short* wxcat = (short*)(ws + off); off += (size_t)NR * NI * 2; // 8 MB (dead after gemm_x)
  short* whcat = (short*)(ws + off); off += (size_t)NR * NH * 2;
  float* bias  = (float*)(ws + off); off += NR * 4;
  unsigned int* flags = (unsigned int*)(ws + off); off += NGRP * WPG * FLAGSTRIDE * 4;
  (void)ws_size; (void)in_sizes; (void)n_in; (void)out_size;

  // rotating h slots ALIAS xbf+wxcat (dead once lstm_persist runs):
  // 4 grp x 512 slots x 33792 B = 69.2 MB <= 75.5 MB available.
  char* hb = (char*)xbf;

  float* out = (float*)d_out;

  (void)hipFuncSetAttribute((const void*)lstm_persist,
                            hipFuncAttributeMaxDynamicSharedMemorySize, LDS_BYTES);

  k_convert_x<<<(int)(SB * NI / 4 / 256), 256, 0, stream>>>(x, xbf);
  WPtrs wp = {wxi, wxf, wxc, wxo, whi, whf, whc, who};
  k_pack_w<<<(NR * NI / 4) / 256, 256, 0, stream>>>(wp, wxcat, whcat);
  BPtrs bp = {bxi, bhi, bi, bxf, bhf, bf, bxc, bhc, bc, bxo, bho, bo};
  k_init<<<NR / 256, 256, 0, stream>>>(bp, bias, flags);

  gemm_x<<<dim3(SB / 128, NR / 128), 256, 0, stream>>>(xbf, wxcat, bias, gxp);

  lstm_persist<<<NGRP * WPG, 256, LDS_BYTES, stream>>>(gxp, whcat, hb, flags, out);
}